// Round 7
// baseline (735.292 us; speedup 1.0000x reference)
//
#include <hip/hip_runtime.h>
#include <stdint.h>

// Problem constants
#define ZSIZE   8388608      // 32*256*32*32
#define NPIX    32768        // 32*32*32
#define IDX_OFF ZSIZE        // idx output offset (floats) in d_out
#define LOSS_OFF (ZSIZE + NPIX)
#define ET_OFF  1024         // Et scratch offset (words) in d_out[0..ZSIZE) region
                             // d_out[0..1024) = se scratch; both overwritten by kout later.

// async global->LDS, 16B per lane. Per-wave LDS dests must be
// wave-uniform base + lane*16 (true for all uses below; global src may be
// per-lane arbitrary).
typedef const __attribute__((address_space(1))) void gv_t;
typedef __attribute__((address_space(3))) void sv_t;
__device__ __forceinline__ void gl_lds16(const float* g, float* l) {
  __builtin_amdgcn_global_load_lds((gv_t*)g, (sv_t*)l, 16, 0, 0);
}

// ---------------------------------------------------------------------------
// ktr: transpose embedding E[1024][256] -> Et[256][1024] in d_out scratch
// ---------------------------------------------------------------------------
__global__ __launch_bounds__(256) void ktr(const float* __restrict__ E,
                                           float* __restrict__ out) {
  __shared__ float tile[64][65];
  const int k0 = blockIdx.x * 64;
  const int c0 = blockIdx.y * 64;
  const int t = threadIdx.x;
  #pragma unroll
  for (int i = 0; i < 4; i++) {
    int f = t + 256 * i;
    int r = f >> 4, q = f & 15;
    float4 e = *(const float4*)(E + (k0 + r) * 256 + c0 + 4 * q);
    tile[r][4 * q + 0] = e.x; tile[r][4 * q + 1] = e.y;
    tile[r][4 * q + 2] = e.z; tile[r][4 * q + 3] = e.w;
  }
  __syncthreads();
  #pragma unroll
  for (int i = 0; i < 4; i++) {
    int f = t + 256 * i;
    int cr = f >> 4, kq = f & 15;
    float4 o;
    o.x = tile[4 * kq + 0][cr];
    o.y = tile[4 * kq + 1][cr];
    o.z = tile[4 * kq + 2][cr];
    o.w = tile[4 * kq + 3][cr];
    *(float4*)(out + ET_OFF + (c0 + cr) * 1024 + k0 + 4 * kq) = o;
  }
}

// ---------------------------------------------------------------------------
// kse: se[k] = ascending-c sequential sum of E[k][c]^2 (order must match
// reference fp32 chain — idx bit-faithfulness). Coalesced via Et.
// ---------------------------------------------------------------------------
__global__ __launch_bounds__(256) void kse(float* __restrict__ out) {
  const int k = blockIdx.x * 256 + threadIdx.x;
  const float* Et = out + ET_OFF;
  float acc = 0.0f;
  #pragma unroll 8
  for (int c = 0; c < 256; c++) {
    float v = Et[c * 1024 + k];
    acc = __fadd_rn(acc, __fmul_rn(v, v));
  }
  out[k] = acc;
}

// ---------------------------------------------------------------------------
// kmain: fused distance GEMM + argmin.
// R6's 16px x 8code tile (wave w = t>>6 owns pixel rows 4w..4w+3; lane = t&63
// owns codes {4*lane + 256*j0 + l} per kt-tile of 512) on R3's spill-free
// skeleton (single Es buffer, barrier-stage-barrier-compute, plain loops).
// - Vs reads: 4 b128 wave-uniform broadcasts (near-free on the LDS pipe).
// - Es reads: 2 b128 at float4-index f=lane (stride-1, conflict-free).
// - sz: each wave's lanes 0..15 compute their own 16 pixels from GLOBAL
//   (ascending-c mul-then-add, bit-identical chain), kept in a REGISTER and
//   broadcast via __shfl in the epilogue. R6 parked this in LDS szs[64],
//   pushing LDS to 82432 > 81920 -> 1 block/CU -> exposed stage drains.
// LDS = 64+16 = exactly 80 KB -> 2 blocks/CU (VGPR 180 -> 2 waves/SIMD ok).
// dist = fl(fl(se+sz) - fl(2*dot)), dot = ascending-c fp32 FMA chain;
// argmin first-index; cross-lane merge via 64-lane shfl_xor butterfly with
// (d,idx) lexicographic min.
// ---------------------------------------------------------------------------
__global__ __launch_bounds__(256, 2) void kmain(const float* __restrict__ z,
                                                float* __restrict__ out) {
  __shared__ __attribute__((aligned(16))) float Vs[16 * 1024];  // 64 KB
  __shared__ __attribute__((aligned(16))) float Es[8 * 512];    // 16 KB

  const int t = threadIdx.x;
  const int ccg = blockIdx.x;       // 0..15
  const int b = blockIdx.y;         // 0..31
  const int cc0 = ccg * 16;
  const int w = t >> 6;             // wave = pixel-row group (rows 4w..4w+3)
  const int lane = t & 63;          // code lane
  const float* zb = z + (size_t)b * 262144;
  const float* se_g = out;
  const float* Et_g = out + ET_OFF;

  // ---- issue V-tile staging: 16 contiguous rows of 1024 floats (async) ----
  #pragma unroll
  for (int i2 = 0; i2 < 16; i2++) {
    int f = t + 256 * i2;           // 0..4095 float4s
    int r = f >> 8, q = f & 255;
    gl_lds16(zb + (cc0 + r) * 1024 + 4 * q, Vs + r * 1024 + 4 * q);
  }

  // ---- sz: wave w's lanes 0..15 compute pixel 16w+lane from GLOBAL ----
  // pixel p = r_local*4 + w0 with r_local = lane>>2, w0 = lane&3; row 4w+r_local.
  float szmine = 0.0f;
  if (lane < 16) {
    const float* src = zb + (cc0 + 4 * w + (lane >> 2)) * 1024 + (lane & 3);
    #pragma unroll 8
    for (int c = 0; c < 256; c++) {
      float v = src[4 * c];
      szmine = __fadd_rn(szmine, __fmul_rn(v, v));
    }
  }

  float bestd[16];
  int besti[16];
  #pragma unroll
  for (int i = 0; i < 16; i++) { bestd[i] = 3.4e38f; besti[i] = 0; }

  for (int kt = 0; kt < 2; kt++) {
    const int k0 = kt * 512;
    float acc[16][8];
    #pragma unroll
    for (int i = 0; i < 16; i++)
      #pragma unroll
      for (int j = 0; j < 8; j++) acc[i][j] = 0.0f;

    for (int ci = 0; ci < 32; ci++) {
      const int c0 = ci * 8;
      __syncthreads();              // previous chunk's Es readers done
      // stage Es[8][512]: c-rows c0..c0+7, codes k0..k0+511
      #pragma unroll
      for (int i2 = 0; i2 < 4; i2++) {
        int f = t + 256 * i2;       // 0..1023 float4s
        int r = f >> 7, q = f & 127;
        gl_lds16(Et_g + (c0 + r) * 1024 + k0 + 4 * q, Es + r * 512 + 4 * q);
      }
      __syncthreads();              // chunk resident

      #pragma unroll
      for (int c = 0; c < 8; c++) {
        const int cw = 4 * (c0 + c);
        float4 v0 = *(const float4*)(Vs + (4 * w + 0) * 1024 + cw);
        float4 v1 = *(const float4*)(Vs + (4 * w + 1) * 1024 + cw);
        float4 v2 = *(const float4*)(Vs + (4 * w + 2) * 1024 + cw);
        float4 v3 = *(const float4*)(Vs + (4 * w + 3) * 1024 + cw);
        float4 e0 = *(const float4*)(Es + c * 512 + 4 * lane);
        float4 e1 = *(const float4*)(Es + c * 512 + 256 + 4 * lane);
        float vv[16] = {v0.x, v0.y, v0.z, v0.w, v1.x, v1.y, v1.z, v1.w,
                        v2.x, v2.y, v2.z, v2.w, v3.x, v3.y, v3.z, v3.w};
        float ee[8] = {e0.x, e0.y, e0.z, e0.w, e1.x, e1.y, e1.z, e1.w};
        #pragma unroll
        for (int i = 0; i < 16; i++)
          #pragma unroll
          for (int j = 0; j < 8; j++)
            acc[i][j] = __fmaf_rn(vv[i], ee[j], acc[i][j]);
      }
    }

    // ---- epilogue kt: dist + running argmin ----
    // acc[i][4*j0+l] is code k0 + 4*lane + 256*j0 + l; pixel i of wave w has
    // its sz in lane i's szmine (broadcast via shfl, i is unroll-constant).
    float4 s0 = *(const float4*)(se_g + k0 + 4 * lane);
    float4 s1 = *(const float4*)(se_g + k0 + 256 + 4 * lane);
    float se8[8] = {s0.x, s0.y, s0.z, s0.w, s1.x, s1.y, s1.z, s1.w};
    #pragma unroll
    for (int i = 0; i < 16; i++) {
      float szv = __shfl(szmine, i, 64);
      #pragma unroll
      for (int j0 = 0; j0 < 2; j0++)
        #pragma unroll
        for (int l = 0; l < 4; l++) {
          int j = 4 * j0 + l;
          float d = __fsub_rn(__fadd_rn(se8[j], szv),
                              __fmul_rn(2.0f, acc[i][j]));
          // ascending-code iteration + strict < == first-index argmin
          if (d < bestd[i]) { bestd[i] = d; besti[i] = k0 + 4 * lane + 256 * j0 + l; }
        }
    }
  }

  // ---- cross-lane argmin merge: 64-lane butterfly, (d,idx) lexicographic ----
  #pragma unroll
  for (int i = 0; i < 16; i++) {
    float bd = bestd[i]; int bi = besti[i];
    #pragma unroll
    for (int m = 32; m >= 1; m >>= 1) {
      float d2 = __shfl_xor(bd, m, 64);
      int i2 = __shfl_xor(bi, m, 64);
      if (d2 < bd || (d2 == bd && i2 < bi)) { bd = d2; bi = i2; }
    }
    if (lane == 0) {
      int r = 4 * w + (i >> 2), w0 = i & 3;
      int n = w0 * 256 + cc0 + r;
      out[IDX_OFF + b * 1024 + n] = (float)bi;
    }
  }
}

// ---------------------------------------------------------------------------
// kout: z_q_st = fl(zp + fl(zq - zp)); per-block loss partial -> d_ws
// ---------------------------------------------------------------------------
__global__ __launch_bounds__(256) void kout(const float* __restrict__ z,
                                            const float* __restrict__ E,
                                            float* __restrict__ out,
                                            float* __restrict__ ws) {
  __shared__ float red[4];
  const int t = threadIdx.x;
  const size_t g4 = (size_t)blockIdx.x * 256 + t;
  const size_t g = g4 * 4;
  const int b = (int)(g >> 18);
  const int c = (int)((g >> 10) & 255);
  const int n = (int)(g & 1023);

  float4 zp = *(const float4*)(z + g);
  float4 idxf = *(const float4*)(out + IDX_OFF + b * 1024 + n);
  int i0 = (int)idxf.x, i1 = (int)idxf.y, i2 = (int)idxf.z, i3 = (int)idxf.w;
  float q0 = E[i0 * 256 + c];
  float q1 = E[i1 * 256 + c];
  float q2 = E[i2 * 256 + c];
  float q3 = E[i3 * 256 + c];
  float d0 = __fsub_rn(q0, zp.x);
  float d1 = __fsub_rn(q1, zp.y);
  float d2 = __fsub_rn(q2, zp.z);
  float d3 = __fsub_rn(q3, zp.w);
  float4 o;
  o.x = __fadd_rn(zp.x, d0);
  o.y = __fadd_rn(zp.y, d1);
  o.z = __fadd_rn(zp.z, d2);
  o.w = __fadd_rn(zp.w, d3);
  *(float4*)(out + g) = o;

  float s = d0 * d0 + d1 * d1 + d2 * d2 + d3 * d3;
  #pragma unroll
  for (int off = 32; off > 0; off >>= 1) s += __shfl_down(s, off);
  if ((t & 63) == 0) red[t >> 6] = s;
  __syncthreads();
  if (t == 0) ws[blockIdx.x] = red[0] + red[1] + red[2] + red[3];
}

// ---------------------------------------------------------------------------
// kfin: loss = 1.25 * (sum(ws)/N)
// ---------------------------------------------------------------------------
__global__ __launch_bounds__(256) void kfin(const float* __restrict__ ws,
                                            float* __restrict__ out) {
  __shared__ float red[4];
  const int t = threadIdx.x;
  float s = 0.0f;
  #pragma unroll
  for (int i = 0; i < 32; i++) s += ws[t + 256 * i];
  #pragma unroll
  for (int off = 32; off > 0; off >>= 1) s += __shfl_down(s, off);
  if ((t & 63) == 0) red[t >> 6] = s;
  __syncthreads();
  if (t == 0) {
    float S = red[0] + red[1] + red[2] + red[3];
    float m = S / 8388608.0f;
    out[LOSS_OFF] = __fadd_rn(m, __fmul_rn(0.25f, m));
  }
}

extern "C" void kernel_launch(void* const* d_in, const int* in_sizes, int n_in,
                              void* d_out, int out_size, void* d_ws, size_t ws_size,
                              hipStream_t stream) {
  const float* z = (const float*)d_in[0];    // [32,256,32,32]
  const float* E = (const float*)d_in[1];    // [1024,256]
  float* out = (float*)d_out;
  float* ws = (float*)d_ws;                  // 8192 floats of partials

  ktr<<<dim3(16, 4), 256, 0, stream>>>(E, out);
  kse<<<dim3(4), 256, 0, stream>>>(out);
  kmain<<<dim3(16, 32), 256, 0, stream>>>(z, out);
  kout<<<dim3(8192), 256, 0, stream>>>(z, E, out, ws);
  kfin<<<dim3(1), 256, 0, stream>>>(ws, out);
}

// Round 8
// 364.114 us; speedup vs baseline: 2.0194x; 2.0194x over previous
//
#include <hip/hip_runtime.h>
#include <stdint.h>

// Problem constants
#define ZSIZE   8388608      // 32*256*32*32
#define NPIX    32768        // 32*32*32
#define IDX_OFF ZSIZE        // idx output offset (floats) in d_out
#define LOSS_OFF (ZSIZE + NPIX)
#define ET_OFF  1024         // Et scratch offset (words) in d_out[0..ZSIZE) region
                             // d_out[0..1024) = se scratch; both overwritten by kout later.

// async global->LDS, 16B per lane. Per-wave LDS dests must be
// wave-uniform base + lane*16 (true for all uses below).
typedef const __attribute__((address_space(1))) void gv_t;
typedef __attribute__((address_space(3))) void sv_t;
__device__ __forceinline__ void gl_lds16(const float* g, float* l) {
  __builtin_amdgcn_global_load_lds((gv_t*)g, (sv_t*)l, 16, 0, 0);
}

// ---------------------------------------------------------------------------
// ktr: transpose embedding E[1024][256] -> Et[256][1024] in d_out scratch
// ---------------------------------------------------------------------------
__global__ __launch_bounds__(256) void ktr(const float* __restrict__ E,
                                           float* __restrict__ out) {
  __shared__ float tile[64][65];
  const int k0 = blockIdx.x * 64;
  const int c0 = blockIdx.y * 64;
  const int t = threadIdx.x;
  #pragma unroll
  for (int i = 0; i < 4; i++) {
    int f = t + 256 * i;
    int r = f >> 4, q = f & 15;
    float4 e = *(const float4*)(E + (k0 + r) * 256 + c0 + 4 * q);
    tile[r][4 * q + 0] = e.x; tile[r][4 * q + 1] = e.y;
    tile[r][4 * q + 2] = e.z; tile[r][4 * q + 3] = e.w;
  }
  __syncthreads();
  #pragma unroll
  for (int i = 0; i < 4; i++) {
    int f = t + 256 * i;
    int cr = f >> 4, kq = f & 15;
    float4 o;
    o.x = tile[4 * kq + 0][cr];
    o.y = tile[4 * kq + 1][cr];
    o.z = tile[4 * kq + 2][cr];
    o.w = tile[4 * kq + 3][cr];
    *(float4*)(out + ET_OFF + (c0 + cr) * 1024 + k0 + 4 * kq) = o;
  }
}

// ---------------------------------------------------------------------------
// kse: se[k] = ascending-c sequential sum of E[k][c]^2 (order must match
// reference fp32 chain — idx bit-faithfulness). Coalesced via Et.
// ---------------------------------------------------------------------------
__global__ __launch_bounds__(256) void kse(float* __restrict__ out) {
  const int k = blockIdx.x * 256 + threadIdx.x;
  const float* Et = out + ET_OFF;
  float acc = 0.0f;
  #pragma unroll 8
  for (int c = 0; c < 256; c++) {
    float v = Et[c * 1024 + k];
    acc = __fadd_rn(acc, __fmul_rn(v, v));
  }
  out[k] = acc;
}

// ---------------------------------------------------------------------------
// kmain: fused distance GEMM + argmin.
// 16px x 4code micro-tile (acc[16][4] = 64 AGPRs) — REGISTER-SAFE version of
// the R6 tile. R4/R5/R7 all spilled (66/360/905 MB scratch writes) because
// the 128-AGPR acc plus ~130 arch VGPRs exceeded the (256,2) budget; at 64
// AGPR + ~66 arch there is structural margin.
// Wave w = t>>6 owns pixel rows 4w..4w+3 (16 px); lane = t&63 owns codes
// {256*h + 4*lane + l} for half-tile h = 0..3.
// - Vs reads: 4 b128 wave-uniform broadcasts per c (component c of 16 px).
// - Es reads: 1 b128 per c at float4-index c*64+lane (stride-1, no conflict).
// - Es chunk = 16 c-rows x 256 codes (16 KB); 64 stage phases total.
// - sz: lanes 0..15 of each wave compute their 16 pixels from GLOBAL
//   (ascending-c mul-then-add, bit-identical), kept in a register and
//   broadcast via __shfl in the epilogue (no LDS — R6's szs[] pushed LDS
//   past 80 KB -> 1 block/CU).
// LDS = 64 + 16 = exactly 80 KB -> 2 blocks/CU.
// dist = fl(fl(se+sz) - fl(2*dot)), dot = ascending-c fp32 FMA chain;
// argmin first-index; cross-lane merge via 64-lane shfl_xor butterfly with
// (d,idx) lexicographic min.
// ---------------------------------------------------------------------------
__global__ __launch_bounds__(256, 2) void kmain(const float* __restrict__ z,
                                                float* __restrict__ out) {
  __shared__ __attribute__((aligned(16))) float Vs[16 * 1024];  // 64 KB
  __shared__ __attribute__((aligned(16))) float Es[16 * 256];   // 16 KB

  const int t = threadIdx.x;
  const int ccg = blockIdx.x;       // 0..15
  const int b = blockIdx.y;         // 0..31
  const int cc0 = ccg * 16;
  const int w = t >> 6;             // wave = pixel-row group (rows 4w..4w+3)
  const int lane = t & 63;          // code lane
  const float* zb = z + (size_t)b * 262144;
  const float* se_g = out;
  const float* Et_g = out + ET_OFF;

  // ---- issue V-tile staging: 16 contiguous rows of 1024 floats (async) ----
  #pragma unroll
  for (int i2 = 0; i2 < 16; i2++) {
    int f = t + 256 * i2;           // 0..4095 float4s
    int r = f >> 8, q = f & 255;
    gl_lds16(zb + (cc0 + r) * 1024 + 4 * q, Vs + r * 1024 + 4 * q);
  }

  // ---- sz: wave w's lanes 0..15 compute pixel 16w+lane from GLOBAL ----
  float szmine = 0.0f;
  if (lane < 16) {
    const float* src = zb + (cc0 + 4 * w + (lane >> 2)) * 1024 + (lane & 3);
    #pragma unroll 8
    for (int c = 0; c < 256; c++) {
      float v = src[4 * c];
      szmine = __fadd_rn(szmine, __fmul_rn(v, v));
    }
  }

  float bestd[16];
  int besti[16];
  #pragma unroll
  for (int i = 0; i < 16; i++) { bestd[i] = 3.4e38f; besti[i] = 0; }

  for (int h = 0; h < 4; h++) {     // half-tile: codes [256h, 256h+256)
    const int kh = h * 256;
    float acc[16][4];
    #pragma unroll
    for (int i = 0; i < 16; i++)
      #pragma unroll
      for (int l = 0; l < 4; l++) acc[i][l] = 0.0f;

    for (int ci = 0; ci < 16; ci++) {
      const int c0 = ci * 16;
      __syncthreads();              // previous chunk's Es readers done
      // stage Es[16][256]: c-rows c0..c0+15, codes kh..kh+255
      #pragma unroll
      for (int i2 = 0; i2 < 4; i2++) {
        int f = t + 256 * i2;       // 0..1023 float4s
        int r = f >> 6, q = f & 63;
        gl_lds16(Et_g + (c0 + r) * 1024 + kh + 4 * q, Es + r * 256 + 4 * q);
      }
      __syncthreads();              // chunk resident

      #pragma unroll
      for (int c = 0; c < 16; c++) {
        const int cw = 4 * (c0 + c);
        // component c of the wave's 16 pixels: row 4w+rl, w-offset wo ->
        // Vs[(4w+rl)*1024 + cw + wo]  (wave-uniform b128 broadcasts)
        float4 v0 = *(const float4*)(Vs + (4 * w + 0) * 1024 + cw);
        float4 v1 = *(const float4*)(Vs + (4 * w + 1) * 1024 + cw);
        float4 v2 = *(const float4*)(Vs + (4 * w + 2) * 1024 + cw);
        float4 v3 = *(const float4*)(Vs + (4 * w + 3) * 1024 + cw);
        float4 e = *(const float4*)(Es + c * 256 + 4 * lane);
        #pragma unroll
        for (int l = 0; l < 4; l++) {
          float el = (l == 0) ? e.x : (l == 1) ? e.y : (l == 2) ? e.z : e.w;
          acc[0][l]  = __fmaf_rn(v0.x, el, acc[0][l]);
          acc[1][l]  = __fmaf_rn(v0.y, el, acc[1][l]);
          acc[2][l]  = __fmaf_rn(v0.z, el, acc[2][l]);
          acc[3][l]  = __fmaf_rn(v0.w, el, acc[3][l]);
          acc[4][l]  = __fmaf_rn(v1.x, el, acc[4][l]);
          acc[5][l]  = __fmaf_rn(v1.y, el, acc[5][l]);
          acc[6][l]  = __fmaf_rn(v1.z, el, acc[6][l]);
          acc[7][l]  = __fmaf_rn(v1.w, el, acc[7][l]);
          acc[8][l]  = __fmaf_rn(v2.x, el, acc[8][l]);
          acc[9][l]  = __fmaf_rn(v2.y, el, acc[9][l]);
          acc[10][l] = __fmaf_rn(v2.z, el, acc[10][l]);
          acc[11][l] = __fmaf_rn(v2.w, el, acc[11][l]);
          acc[12][l] = __fmaf_rn(v3.x, el, acc[12][l]);
          acc[13][l] = __fmaf_rn(v3.y, el, acc[13][l]);
          acc[14][l] = __fmaf_rn(v3.z, el, acc[14][l]);
          acc[15][l] = __fmaf_rn(v3.w, el, acc[15][l]);
        }
      }
    }

    // ---- epilogue h: dist + running argmin ----
    // acc[i][l] is code kh + 4*lane + l; pixel i: row 4w+(i>>2), w0 = i&3.
    float4 se4 = *(const float4*)(se_g + kh + 4 * lane);
    #pragma unroll
    for (int i = 0; i < 16; i++) {
      float szv = __shfl(szmine, i, 64);
      #pragma unroll
      for (int l = 0; l < 4; l++) {
        float sel = (l == 0) ? se4.x : (l == 1) ? se4.y : (l == 2) ? se4.z : se4.w;
        float d = __fsub_rn(__fadd_rn(sel, szv), __fmul_rn(2.0f, acc[i][l]));
        // h ascending + l ascending + strict < == first-index argmin
        if (d < bestd[i]) { bestd[i] = d; besti[i] = kh + 4 * lane + l; }
      }
    }
  }

  // ---- cross-lane argmin merge: 64-lane butterfly, (d,idx) lexicographic ----
  #pragma unroll
  for (int i = 0; i < 16; i++) {
    float bd = bestd[i]; int bi = besti[i];
    #pragma unroll
    for (int m = 32; m >= 1; m >>= 1) {
      float d2 = __shfl_xor(bd, m, 64);
      int i2 = __shfl_xor(bi, m, 64);
      if (d2 < bd || (d2 == bd && i2 < bi)) { bd = d2; bi = i2; }
    }
    if (lane == 0) {
      int r = 4 * w + (i >> 2), w0 = i & 3;
      int n = w0 * 256 + cc0 + r;
      out[IDX_OFF + b * 1024 + n] = (float)bi;
    }
  }
}

// ---------------------------------------------------------------------------
// kout: z_q_st = fl(zp + fl(zq - zp)); per-block loss partial -> d_ws
// ---------------------------------------------------------------------------
__global__ __launch_bounds__(256) void kout(const float* __restrict__ z,
                                            const float* __restrict__ E,
                                            float* __restrict__ out,
                                            float* __restrict__ ws) {
  __shared__ float red[4];
  const int t = threadIdx.x;
  const size_t g4 = (size_t)blockIdx.x * 256 + t;
  const size_t g = g4 * 4;
  const int b = (int)(g >> 18);
  const int c = (int)((g >> 10) & 255);
  const int n = (int)(g & 1023);

  float4 zp = *(const float4*)(z + g);
  float4 idxf = *(const float4*)(out + IDX_OFF + b * 1024 + n);
  int i0 = (int)idxf.x, i1 = (int)idxf.y, i2 = (int)idxf.z, i3 = (int)idxf.w;
  float q0 = E[i0 * 256 + c];
  float q1 = E[i1 * 256 + c];
  float q2 = E[i2 * 256 + c];
  float q3 = E[i3 * 256 + c];
  float d0 = __fsub_rn(q0, zp.x);
  float d1 = __fsub_rn(q1, zp.y);
  float d2 = __fsub_rn(q2, zp.z);
  float d3 = __fsub_rn(q3, zp.w);
  float4 o;
  o.x = __fadd_rn(zp.x, d0);
  o.y = __fadd_rn(zp.y, d1);
  o.z = __fadd_rn(zp.z, d2);
  o.w = __fadd_rn(zp.w, d3);
  *(float4*)(out + g) = o;

  float s = d0 * d0 + d1 * d1 + d2 * d2 + d3 * d3;
  #pragma unroll
  for (int off = 32; off > 0; off >>= 1) s += __shfl_down(s, off);
  if ((t & 63) == 0) red[t >> 6] = s;
  __syncthreads();
  if (t == 0) ws[blockIdx.x] = red[0] + red[1] + red[2] + red[3];
}

// ---------------------------------------------------------------------------
// kfin: loss = 1.25 * (sum(ws)/N)
// ---------------------------------------------------------------------------
__global__ __launch_bounds__(256) void kfin(const float* __restrict__ ws,
                                            float* __restrict__ out) {
  __shared__ float red[4];
  const int t = threadIdx.x;
  float s = 0.0f;
  #pragma unroll
  for (int i = 0; i < 32; i++) s += ws[t + 256 * i];
  #pragma unroll
  for (int off = 32; off > 0; off >>= 1) s += __shfl_down(s, off);
  if ((t & 63) == 0) red[t >> 6] = s;
  __syncthreads();
  if (t == 0) {
    float S = red[0] + red[1] + red[2] + red[3];
    float m = S / 8388608.0f;
    out[LOSS_OFF] = __fadd_rn(m, __fmul_rn(0.25f, m));
  }
}

extern "C" void kernel_launch(void* const* d_in, const int* in_sizes, int n_in,
                              void* d_out, int out_size, void* d_ws, size_t ws_size,
                              hipStream_t stream) {
  const float* z = (const float*)d_in[0];    // [32,256,32,32]
  const float* E = (const float*)d_in[1];    // [1024,256]
  float* out = (float*)d_out;
  float* ws = (float*)d_ws;                  // 8192 floats of partials

  ktr<<<dim3(16, 4), 256, 0, stream>>>(E, out);
  kse<<<dim3(4), 256, 0, stream>>>(out);
  kmain<<<dim3(16, 32), 256, 0, stream>>>(z, out);
  kout<<<dim3(8192), 256, 0, stream>>>(z, E, out, ws);
  kfin<<<dim3(1), 256, 0, stream>>>(ws, out);
}